// Round 5
// baseline (2408.355 us; speedup 1.0000x reference)
//
#include <hip/hip_runtime.h>
#include <hip/hip_cooperative_groups.h>

namespace cg = cooperative_groups;

#define NROWS 8192
#define RPB   64
#define TPB   512
#define NBLK  128

// workspace layout (float offsets)
#define OFF_W1   0          // 1024
#define OFF_W2   1024       // 1024
#define OFF_WIN  2048       // 102*34 = 3468
#define OFF_WFC2 5516       // 1024
#define OFF_M    6540       // 32*34 = 1088
#define OFF_B12  7628       // 32
#define OFF_BIN  7660       // 102
#define OFF_B2   7762       // 32
#define OFF_BFC2 7794       // 32
#define OFF_LNG  7826       // 32
#define OFF_LNB  7858       // 32
#define OFF_QKV0 8192
#define QKVN     (NROWS*102)          // feature-major: qkv[e][row]
#define OFF_QKV1 (OFF_QKV0 + QKVN)
#define OFF_HNEW (OFF_QKV1 + QKVN)   // feature-major: hnew[j][row], 32*NROWS

__global__ __launch_bounds__(256) void setup_kernel(
    const float* __restrict__ W_x2h, const float* __restrict__ b_x2h,
    const float* __restrict__ W_h2h, const float* __restrict__ b_h2h,
    const float* __restrict__ W_fc2, const float* __restrict__ b_fc2,
    const float* __restrict__ ln_g,  const float* __restrict__ ln_b,
    const float* __restrict__ W_fcsa,const float* __restrict__ b_fcsa,
    const float* __restrict__ W_in,  const float* __restrict__ b_in,
    const float* __restrict__ W_out, const float* __restrict__ b_out,
    float* __restrict__ ws)
{
  int t = blockIdx.x*blockDim.x + threadIdx.x;
  int stride = gridDim.x*blockDim.x;
  for (int i=t;i<1024;i+=stride) ws[OFF_W1+i]   = W_x2h[i];
  for (int i=t;i<1024;i+=stride) ws[OFF_W2+i]   = W_h2h[i];
  for (int i=t;i<3468;i+=stride) ws[OFF_WIN+i]  = W_in[i];
  for (int i=t;i<1024;i+=stride) ws[OFF_WFC2+i] = W_fc2[i];
  for (int i=t;i<32;i+=stride)   ws[OFF_B12+i]  = b_x2h[i] + b_h2h[i];
  for (int i=t;i<102;i+=stride)  ws[OFF_BIN+i]  = b_in[i];
  for (int i=t;i<32;i+=stride)   ws[OFF_BFC2+i] = b_fc2[i];
  for (int i=t;i<32;i+=stride)   ws[OFF_LNG+i]  = ln_g[i];
  for (int i=t;i<32;i+=stride)   ws[OFF_LNB+i]  = ln_b[i];
  // M = W_fcsa (32x34) @ W_out (34x34)
  for (int idx=t; idx<1088; idx+=stride) {
    int j = idx/34, f = idx - j*34;
    float acc = 0.f;
    for (int e=0;e<34;++e)
      acc += W_fcsa[j*34+e] * W_out[e*34+f];
    ws[OFF_M+idx] = acc;
  }
  for (int j=t;j<32;j+=stride){
    float acc = b_fcsa[j];
    for (int e=0;e<34;++e) acc += W_fcsa[j*34+e] * b_out[e];
    ws[OFF_B2+j] = acc;
  }
}

// Persistent cooperative kernel: all 60 iterations in one launch.
// Iteration i = attention/update/pred of step i-1 + tanh-rnn/qkv of step i.
// One grid.sync() per iteration (between qkv writes of iter i and reads of
// iter i+1; double-buffered qkv makes a single sync cover RAW + WAR).
// lane (tid&63) = row; wave id through readfirstlane -> weight reads are
// provably uniform -> s_load (scalar cache), hot across all 60 iterations.
__global__ __launch_bounds__(TPB) void rnn_all(
    float* __restrict__ ws,
    const float* __restrict__ x,
    float* __restrict__ out)
{
  cg::grid_group grid = cg::this_grid();

  const float* W1f   = ws + OFF_W1;
  const float* W2f   = ws + OFF_W2;
  const float* Winf  = ws + OFF_WIN;
  const float* Wfc2f = ws + OFF_WFC2;
  const float* Mf    = ws + OFF_M;
  const float* b12f  = ws + OFF_B12;
  const float* binf  = ws + OFF_BIN;
  const float* b2f   = ws + OFF_B2;
  const float* bfc2f = ws + OFF_BFC2;
  const float* lngf  = ws + OFF_LNG;
  const float* lnbf  = ws + OFF_LNB;
  float* hnewG = ws + OFF_HNEW;

  __shared__ float sS[RPB][13];     // 9 scores
  __shared__ float sO[RPB][35];     // attention output (34)
  __shared__ float sHp[RPB][33];    // h' (post-attention state)
  __shared__ float sG[RPB][33];     // pre-LN fc2 output
  __shared__ float sPred[RPB][33];  // pred (next-step input)
  __shared__ float sHn[RPB][33];    // h_new (tanh output)
  __shared__ float sX[RPB][33];     // staged x chunk (steps 0..9)

  const int tid = threadIdx.x;
  const int lr  = tid & 63;
  const int wu  = __builtin_amdgcn_readfirstlane(tid >> 6);  // wave id, uniform
  const int base= blockIdx.x * RPB;
  const int r   = base + lr;
  const int b   = r >> 12;
  const int p   = r & 4095;
  const int gr  = p >> 6, gc = p & 63;
  const int br  = (gr < 1) ? 1 : ((gr > 62) ? 62 : gr);
  const int bc  = (gc < 1) ? 1 : ((gc > 62) ? 62 : gc);
  const int qrow = (b<<12) + (br<<6) + bc;           // gathered center row

  for (int i = 0; i < 60; ++i) {
    const int stepB = i - 1;
    const int stepA = (i <= 58) ? i : -1;
    const float* qkvR = ws + OFF_QKV0 + (size_t)((i+1)&1)*QKVN;
    float*       qkvW = ws + OFF_QKV0 + (size_t)(i&1)*QKVN;

    if (stepB >= 0) {
      // ---- scores: wave wu does neighbor m=wu (wave 0 also m=8) ----
      for (int m = wu; m < 9; m += 8) {
        int dr = m/3 - 1, dc = (m - (m/3)*3) - 1;
        int nr_  = (b<<12) + ((br+dr)<<6) + (bc+dc);
        float acc = 0.f;
        #pragma unroll
        for (int e=0;e<34;++e)
          acc += qkvR[(size_t)e*NROWS + qrow] * qkvR[(size_t)(34+e)*NROWS + nr_];
        sS[lr][m] = acc * 0.1714985851425088f;       // 1/sqrt(34)
      }
      __syncthreads();
      // ---- softmax (redundant per wave) + o: wave wu handles e = 5*wu.. ----
      if (wu < 7) {
        float sc[9]; float mx = -1e30f;
        #pragma unroll
        for (int m=0;m<9;++m){ sc[m]=sS[lr][m]; mx=fmaxf(mx,sc[m]); }
        float sum=0.f;
        #pragma unroll
        for (int m=0;m<9;++m){ sc[m]=__expf(sc[m]-mx); sum+=sc[m]; }
        float inv = 1.f/sum;
        const int e0 = wu*5;
        const int ne = (e0+5<=34)?5:(34-e0);
        float oacc[5] = {0.f,0.f,0.f,0.f,0.f};
        #pragma unroll
        for (int m=0;m<9;++m){
          int dr = m/3 - 1, dc = (m - (m/3)*3) - 1;
          int nr_ = (b<<12) + ((br+dr)<<6) + (bc+dc);
          float wm = sc[m]*inv;
          #pragma unroll
          for (int k=0;k<5;++k)
            if (k<ne) oacc[k] += wm * qkvR[(size_t)(68+e0+k)*NROWS + nr_];
        }
        #pragma unroll
        for (int k=0;k<5;++k) if (k<ne) sO[lr][e0+k]=oacc[k];
      }
      __syncthreads();
      // ---- h' = h_new + o @ M^T + b2 : wave wu -> j = 4wu..4wu+3 ----
      {
        const int j0 = wu*4;
        float a[4];
        #pragma unroll
        for (int jj=0;jj<4;++jj) a[jj] = b2f[j0+jj];
        #pragma unroll
        for (int e=0;e<34;++e){
          float ov = sO[lr][e];
          #pragma unroll
          for (int jj=0;jj<4;++jj) a[jj] += ov * Mf[(j0+jj)*34+e];   // s_load
        }
        #pragma unroll
        for (int jj=0;jj<4;++jj)
          sHp[lr][j0+jj] = hnewG[(size_t)(j0+jj)*NROWS + r] + a[jj];
      }
      __syncthreads();
      // ---- g = h' @ Wfc2^T + b ----
      {
        const int j0 = wu*4;
        float g[4];
        #pragma unroll
        for (int jj=0;jj<4;++jj) g[jj] = bfc2f[j0+jj];
        #pragma unroll
        for (int i2=0;i2<32;++i2){
          float hv = sHp[lr][i2];
          #pragma unroll
          for (int jj=0;jj<4;++jj) g[jj] += hv * Wfc2f[(j0+jj)*32+i2]; // s_load
        }
        #pragma unroll
        for (int jj=0;jj<4;++jj) sG[lr][j0+jj]=g[jj];
      }
      __syncthreads();
      // ---- layernorm -> sPred ----
      {
        float mu=0.f;
        #pragma unroll
        for (int i2=0;i2<32;++i2) mu += sG[lr][i2];
        mu *= 0.03125f;
        float var=0.f;
        #pragma unroll
        for (int i2=0;i2<32;++i2){ float d=sG[lr][i2]-mu; var += d*d; }
        var *= 0.03125f;
        float rs = rsqrtf(var + 1e-5f);
        const int j0 = wu*4;
        #pragma unroll
        for (int jj=0;jj<4;++jj){
          int j=j0+jj;
          sPred[lr][j] = (sG[lr][j]-mu)*rs*lngf[j] + lnbf[j];
        }
      }
      __syncthreads();
      // ---- coalesced out write (block chunk = 2048 contiguous floats) ----
      {
        size_t obase = ((size_t)stepB*NROWS + base)*32;
        #pragma unroll
        for (int it=0; it<4; ++it){
          int idx = tid + it*TPB;
          out[obase + idx] = sPred[idx>>5][idx&31];
        }
      }
    } else {
      const int j0 = wu*4;
      #pragma unroll
      for (int jj=0;jj<4;++jj) sHp[lr][j0+jj]=0.f;
      __syncthreads();
    }

    if (stepA >= 0) {
      // ---- stage x chunk (coalesced) if this step consumes observations ----
      if (stepA < 10) {
        size_t xbase = ((size_t)stepA*NROWS + base)*32;
        #pragma unroll
        for (int it=0; it<4; ++it){
          int idx = tid + it*TPB;
          sX[idx>>5][idx&31] = x[xbase + idx];
        }
      }
      __syncthreads();
      // ---- h_new = tanh(inp@W1^T + h'@W2^T + b) : wave wu -> j=4wu.. ----
      const int j0 = wu*4;
      float a[4];
      #pragma unroll
      for (int jj=0;jj<4;++jj) a[jj]=b12f[j0+jj];
      if (stepA < 10) {
        #pragma unroll
        for (int i2=0;i2<32;++i2){
          float xv=sX[lr][i2], hv=sHp[lr][i2];
          #pragma unroll
          for (int jj=0;jj<4;++jj)
            a[jj] += xv*W1f[(j0+jj)*32+i2] + hv*W2f[(j0+jj)*32+i2];  // s_load
        }
      } else {
        #pragma unroll
        for (int i2=0;i2<32;++i2){
          float xv=sPred[lr][i2], hv=sHp[lr][i2];
          #pragma unroll
          for (int jj=0;jj<4;++jj)
            a[jj] += xv*W1f[(j0+jj)*32+i2] + hv*W2f[(j0+jj)*32+i2];  // s_load
        }
      }
      #pragma unroll
      for (int jj=0;jj<4;++jj){
        float tv = tanhf(a[jj]);
        sHn[lr][j0+jj]=tv;
        hnewG[(size_t)(j0+jj)*NROWS + r]=tv;    // coalesced (feature-major)
      }
      __syncthreads();
      // ---- qkv = [h_new, pl] @ W_in^T + b_in : wave wu -> e = 13*wu.. ----
      float hn[32];
      #pragma unroll
      for (int f=0;f<32;++f) hn[f]=sHn[lr][f];
      const float pl0 = gr*0.015625f, pl1 = gc*0.015625f;
      const int e0 = wu*13;
      #pragma unroll
      for (int k=0;k<13;++k){
        int e = e0+k;
        if (e < 102) {
          float acc = binf[e];
          #pragma unroll
          for (int f=0;f<32;++f) acc += hn[f]*Winf[e*34+f];          // s_load
          acc += pl0*Winf[e*34+32] + pl1*Winf[e*34+33];
          qkvW[(size_t)e*NROWS + r] = acc;       // coalesced (feature-major)
        }
      }
    }

    grid.sync();   // qkv[i] visible to all blocks; qkv[i-1] reads all retired
  }
}

extern "C" void kernel_launch(void* const* d_in, const int* in_sizes, int n_in,
                              void* d_out, int out_size, void* d_ws, size_t ws_size,
                              hipStream_t stream) {
  const float* x     = (const float*)d_in[0];
  const float* W_x2h = (const float*)d_in[1];
  const float* b_x2h = (const float*)d_in[2];
  const float* W_h2h = (const float*)d_in[3];
  const float* b_h2h = (const float*)d_in[4];
  const float* W_fc2 = (const float*)d_in[5];
  const float* b_fc2 = (const float*)d_in[6];
  const float* ln_g  = (const float*)d_in[7];
  const float* ln_b  = (const float*)d_in[8];
  const float* W_fcsa= (const float*)d_in[9];
  const float* b_fcsa= (const float*)d_in[10];
  const float* W_in  = (const float*)d_in[11];
  const float* b_in  = (const float*)d_in[12];
  const float* W_out = (const float*)d_in[13];
  const float* b_out = (const float*)d_in[14];
  float* ws = (float*)d_ws;
  float* out = (float*)d_out;

  setup_kernel<<<8, 256, 0, stream>>>(W_x2h,b_x2h,W_h2h,b_h2h,W_fc2,b_fc2,ln_g,ln_b,
                                      W_fcsa,b_fcsa,W_in,b_in,W_out,b_out, ws);

  void* args[] = { (void*)&ws, (void*)&x, (void*)&out };
  hipLaunchCooperativeKernel((void*)rnn_all, dim3(NBLK), dim3(TPB), args, 0, stream);
}

// Round 6
// 2023.961 us; speedup vs baseline: 1.1899x; 1.1899x over previous
//
#include <hip/hip_runtime.h>

#define NROWS 8192
#define RPB   64
#define TPB   512
#define NBLK  128

// workspace layout (float offsets)
#define OFF_W1   0          // 1024
#define OFF_W2   1024       // 1024
#define OFF_WIN  2048       // 102*34 = 3468
#define OFF_WFC2 5516       // 1024
#define OFF_M    6540       // 32*34 = 1088
#define OFF_B12  7628       // 32
#define OFF_BIN  7660       // 102
#define OFF_B2   7762       // 32
#define OFF_BFC2 7794       // 32
#define OFF_LNG  7826       // 32
#define OFF_LNB  7858       // 32
#define OFF_BAR  8000       // grid-barrier counter (int), own cacheline
#define OFF_QKV0 8192
#define QKVN     (NROWS*102)          // feature-major: qkv[e][row]
#define OFF_QKV1 (OFF_QKV0 + QKVN)
#define OFF_HNEW (OFF_QKV1 + QKVN)   // feature-major: hnew[j][row], 32*NROWS

__global__ __launch_bounds__(256) void setup_kernel(
    const float* __restrict__ W_x2h, const float* __restrict__ b_x2h,
    const float* __restrict__ W_h2h, const float* __restrict__ b_h2h,
    const float* __restrict__ W_fc2, const float* __restrict__ b_fc2,
    const float* __restrict__ ln_g,  const float* __restrict__ ln_b,
    const float* __restrict__ W_fcsa,const float* __restrict__ b_fcsa,
    const float* __restrict__ W_in,  const float* __restrict__ b_in,
    const float* __restrict__ W_out, const float* __restrict__ b_out,
    float* __restrict__ ws)
{
  int t = blockIdx.x*blockDim.x + threadIdx.x;
  int stride = gridDim.x*blockDim.x;
  if (t == 0) *(int*)(ws + OFF_BAR) = 0;       // zero the grid-barrier counter
  for (int i=t;i<1024;i+=stride) ws[OFF_W1+i]   = W_x2h[i];
  for (int i=t;i<1024;i+=stride) ws[OFF_W2+i]   = W_h2h[i];
  for (int i=t;i<3468;i+=stride) ws[OFF_WIN+i]  = W_in[i];
  for (int i=t;i<1024;i+=stride) ws[OFF_WFC2+i] = W_fc2[i];
  for (int i=t;i<32;i+=stride)   ws[OFF_B12+i]  = b_x2h[i] + b_h2h[i];
  for (int i=t;i<102;i+=stride)  ws[OFF_BIN+i]  = b_in[i];
  for (int i=t;i<32;i+=stride)   ws[OFF_BFC2+i] = b_fc2[i];
  for (int i=t;i<32;i+=stride)   ws[OFF_LNG+i]  = ln_g[i];
  for (int i=t;i<32;i+=stride)   ws[OFF_LNB+i]  = ln_b[i];
  // M = W_fcsa (32x34) @ W_out (34x34)
  for (int idx=t; idx<1088; idx+=stride) {
    int j = idx/34, f = idx - j*34;
    float acc = 0.f;
    for (int e=0;e<34;++e)
      acc += W_fcsa[j*34+e] * W_out[e*34+f];
    ws[OFF_M+idx] = acc;
  }
  for (int j=t;j<32;j+=stride){
    float acc = b_fcsa[j];
    for (int e=0;e<34;++e) acc += W_fcsa[j*34+e] * b_out[e];
    ws[OFF_B2+j] = acc;
  }
}

// Hand-rolled grid barrier. Preconditions: all NBLK blocks co-resident
// (cooperative launch). __syncthreads() drains each wave's vmcnt -> the
// block's stores have reached L2. Thread 0 then: agent-release fence
// (buffer_wbl2, L2 dirty -> L3, visible chip-wide), arrive on a monotonic
// device-scope counter, spin until all blocks of this round arrived,
// agent-acquire fence (buffer_inv: invalidates this CU's L1 + XCD's L2 so
// subsequent reads pull fresh data from L3). Final __syncthreads() releases
// the block's other waves (same CU -> same invalidated L1).
__device__ __forceinline__ void grid_barrier(int* cnt, int target, int tid) {
  __syncthreads();
  if (tid == 0) {
    __builtin_amdgcn_fence(__ATOMIC_RELEASE, "agent");
    __hip_atomic_fetch_add(cnt, 1, __ATOMIC_RELAXED, __HIP_MEMORY_SCOPE_AGENT);
    while (__hip_atomic_load(cnt, __ATOMIC_RELAXED, __HIP_MEMORY_SCOPE_AGENT) < target) {
      __builtin_amdgcn_s_sleep(1);
    }
    __builtin_amdgcn_fence(__ATOMIC_ACQUIRE, "agent");
  }
  __syncthreads();
}

// Persistent cooperative kernel: all 60 iterations in one launch.
// Iteration i = attention/update/pred of step i-1 + tanh-rnn/qkv of step i.
// Only qkv crosses block boundaries (neighbor gather) -> one grid barrier
// per iteration; qkv double-buffer makes a single barrier cover RAW + WAR.
__global__ __launch_bounds__(TPB) void rnn_all(
    float* __restrict__ ws,
    const float* __restrict__ x,
    float* __restrict__ out)
{
  const float* W1f   = ws + OFF_W1;
  const float* W2f   = ws + OFF_W2;
  const float* Winf  = ws + OFF_WIN;
  const float* Wfc2f = ws + OFF_WFC2;
  const float* Mf    = ws + OFF_M;
  const float* b12f  = ws + OFF_B12;
  const float* binf  = ws + OFF_BIN;
  const float* b2f   = ws + OFF_B2;
  const float* bfc2f = ws + OFF_BFC2;
  const float* lngf  = ws + OFF_LNG;
  const float* lnbf  = ws + OFF_LNB;
  float* hnewG = ws + OFF_HNEW;
  int*   bar   = (int*)(ws + OFF_BAR);

  __shared__ float sS[RPB][13];     // 9 scores
  __shared__ float sO[RPB][35];     // attention output (34)
  __shared__ float sHp[RPB][33];    // h' (post-attention state)
  __shared__ float sG[RPB][33];     // pre-LN fc2 output
  __shared__ float sPred[RPB][33];  // pred (next-step input)
  __shared__ float sHn[RPB][33];    // h_new (tanh output)
  __shared__ float sX[RPB][33];     // staged x chunk (steps 0..9)

  const int tid = threadIdx.x;
  const int lr  = tid & 63;
  const int wu  = __builtin_amdgcn_readfirstlane(tid >> 6);  // wave id, uniform
  const int base= blockIdx.x * RPB;
  const int r   = base + lr;
  const int b   = r >> 12;
  const int p   = r & 4095;
  const int gr  = p >> 6, gc = p & 63;
  const int br  = (gr < 1) ? 1 : ((gr > 62) ? 62 : gr);
  const int bc  = (gc < 1) ? 1 : ((gc > 62) ? 62 : gc);
  const int qrow = (b<<12) + (br<<6) + bc;           // gathered center row

  for (int i = 0; i < 60; ++i) {
    const int stepB = i - 1;
    const int stepA = (i <= 58) ? i : -1;
    const float* qkvR = ws + OFF_QKV0 + (size_t)((i+1)&1)*QKVN;
    float*       qkvW = ws + OFF_QKV0 + (size_t)(i&1)*QKVN;

    if (stepB >= 0) {
      // ---- scores: q loaded once, wave wu does neighbor m=wu (w0 also 8) ----
      {
        float qv[34];
        #pragma unroll
        for (int e=0;e<34;++e) qv[e] = qkvR[(size_t)e*NROWS + qrow];
        for (int m = wu; m < 9; m += 8) {
          int dr = m/3 - 1, dc = (m - (m/3)*3) - 1;
          int nr_  = (b<<12) + ((br+dr)<<6) + (bc+dc);
          float acc = 0.f;
          #pragma unroll
          for (int e=0;e<34;++e)
            acc += qv[e] * qkvR[(size_t)(34+e)*NROWS + nr_];
          sS[lr][m] = acc * 0.1714985851425088f;       // 1/sqrt(34)
        }
      }
      __syncthreads();
      // ---- softmax (redundant per wave) + o: wave wu handles e = 5*wu.. ----
      if (wu < 7) {
        float sc[9]; float mx = -1e30f;
        #pragma unroll
        for (int m=0;m<9;++m){ sc[m]=sS[lr][m]; mx=fmaxf(mx,sc[m]); }
        float sum=0.f;
        #pragma unroll
        for (int m=0;m<9;++m){ sc[m]=__expf(sc[m]-mx); sum+=sc[m]; }
        float inv = 1.f/sum;
        const int e0 = wu*5;
        const int ne = (e0+5<=34)?5:(34-e0);
        float oacc[5] = {0.f,0.f,0.f,0.f,0.f};
        #pragma unroll
        for (int m=0;m<9;++m){
          int dr = m/3 - 1, dc = (m - (m/3)*3) - 1;
          int nr_ = (b<<12) + ((br+dr)<<6) + (bc+dc);
          float wm = sc[m]*inv;
          #pragma unroll
          for (int k=0;k<5;++k)
            if (k<ne) oacc[k] += wm * qkvR[(size_t)(68+e0+k)*NROWS + nr_];
        }
        #pragma unroll
        for (int k=0;k<5;++k) if (k<ne) sO[lr][e0+k]=oacc[k];
      }
      __syncthreads();
      // ---- h' = h_new + o @ M^T + b2 : wave wu -> j = 4wu..4wu+3 ----
      {
        const int j0 = wu*4;
        float a[4];
        #pragma unroll
        for (int jj=0;jj<4;++jj) a[jj] = b2f[j0+jj];
        #pragma unroll
        for (int e=0;e<34;++e){
          float ov = sO[lr][e];
          #pragma unroll
          for (int jj=0;jj<4;++jj) a[jj] += ov * Mf[(j0+jj)*34+e];   // s_load
        }
        #pragma unroll
        for (int jj=0;jj<4;++jj)
          sHp[lr][j0+jj] = hnewG[(size_t)(j0+jj)*NROWS + r] + a[jj];
      }
      __syncthreads();
      // ---- g = h' @ Wfc2^T + b ----
      {
        const int j0 = wu*4;
        float g[4];
        #pragma unroll
        for (int jj=0;jj<4;++jj) g[jj] = bfc2f[j0+jj];
        #pragma unroll
        for (int i2=0;i2<32;++i2){
          float hv = sHp[lr][i2];
          #pragma unroll
          for (int jj=0;jj<4;++jj) g[jj] += hv * Wfc2f[(j0+jj)*32+i2]; // s_load
        }
        #pragma unroll
        for (int jj=0;jj<4;++jj) sG[lr][j0+jj]=g[jj];
      }
      __syncthreads();
      // ---- layernorm -> sPred ----
      {
        float mu=0.f;
        #pragma unroll
        for (int i2=0;i2<32;++i2) mu += sG[lr][i2];
        mu *= 0.03125f;
        float var=0.f;
        #pragma unroll
        for (int i2=0;i2<32;++i2){ float d=sG[lr][i2]-mu; var += d*d; }
        var *= 0.03125f;
        float rs = rsqrtf(var + 1e-5f);
        const int j0 = wu*4;
        #pragma unroll
        for (int jj=0;jj<4;++jj){
          int j=j0+jj;
          sPred[lr][j] = (sG[lr][j]-mu)*rs*lngf[j] + lnbf[j];
        }
      }
      __syncthreads();
      // ---- coalesced out write (block chunk = 2048 contiguous floats) ----
      {
        size_t obase = ((size_t)stepB*NROWS + base)*32;
        #pragma unroll
        for (int it=0; it<4; ++it){
          int idx = tid + it*TPB;
          out[obase + idx] = sPred[idx>>5][idx&31];
        }
      }
    } else {
      const int j0 = wu*4;
      #pragma unroll
      for (int jj=0;jj<4;++jj) sHp[lr][j0+jj]=0.f;
      __syncthreads();
    }

    if (stepA >= 0) {
      // ---- stage x chunk (coalesced) if this step consumes observations ----
      if (stepA < 10) {
        size_t xbase = ((size_t)stepA*NROWS + base)*32;
        #pragma unroll
        for (int it=0; it<4; ++it){
          int idx = tid + it*TPB;
          sX[idx>>5][idx&31] = x[xbase + idx];
        }
      }
      __syncthreads();
      // ---- h_new = tanh(inp@W1^T + h'@W2^T + b) : wave wu -> j=4wu.. ----
      const int j0 = wu*4;
      float a[4];
      #pragma unroll
      for (int jj=0;jj<4;++jj) a[jj]=b12f[j0+jj];
      if (stepA < 10) {
        #pragma unroll
        for (int i2=0;i2<32;++i2){
          float xv=sX[lr][i2], hv=sHp[lr][i2];
          #pragma unroll
          for (int jj=0;jj<4;++jj)
            a[jj] += xv*W1f[(j0+jj)*32+i2] + hv*W2f[(j0+jj)*32+i2];  // s_load
        }
      } else {
        #pragma unroll
        for (int i2=0;i2<32;++i2){
          float xv=sPred[lr][i2], hv=sHp[lr][i2];
          #pragma unroll
          for (int jj=0;jj<4;++jj)
            a[jj] += xv*W1f[(j0+jj)*32+i2] + hv*W2f[(j0+jj)*32+i2];  // s_load
        }
      }
      #pragma unroll
      for (int jj=0;jj<4;++jj){
        float tv = tanhf(a[jj]);
        sHn[lr][j0+jj]=tv;
        hnewG[(size_t)(j0+jj)*NROWS + r]=tv;    // coalesced (feature-major)
      }
      __syncthreads();
      // ---- qkv = [h_new, pl] @ W_in^T + b_in : wave wu -> e = 13*wu.. ----
      float hn[32];
      #pragma unroll
      for (int f=0;f<32;++f) hn[f]=sHn[lr][f];
      const float pl0 = gr*0.015625f, pl1 = gc*0.015625f;
      const int e0 = wu*13;
      #pragma unroll
      for (int k=0;k<13;++k){
        int e = e0+k;
        if (e < 102) {
          float acc = binf[e];
          #pragma unroll
          for (int f=0;f<32;++f) acc += hn[f]*Winf[e*34+f];          // s_load
          acc += pl0*Winf[e*34+32] + pl1*Winf[e*34+33];
          qkvW[(size_t)e*NROWS + r] = acc;       // coalesced (feature-major)
        }
      }
    }

    if (i < 59)
      grid_barrier(bar, NBLK*(i+1), tid);   // qkv[i] -> visible; qkv[i-1] reads retired
  }
}

extern "C" void kernel_launch(void* const* d_in, const int* in_sizes, int n_in,
                              void* d_out, int out_size, void* d_ws, size_t ws_size,
                              hipStream_t stream) {
  const float* x     = (const float*)d_in[0];
  const float* W_x2h = (const float*)d_in[1];
  const float* b_x2h = (const float*)d_in[2];
  const float* W_h2h = (const float*)d_in[3];
  const float* b_h2h = (const float*)d_in[4];
  const float* W_fc2 = (const float*)d_in[5];
  const float* b_fc2 = (const float*)d_in[6];
  const float* ln_g  = (const float*)d_in[7];
  const float* ln_b  = (const float*)d_in[8];
  const float* W_fcsa= (const float*)d_in[9];
  const float* b_fcsa= (const float*)d_in[10];
  const float* W_in  = (const float*)d_in[11];
  const float* b_in  = (const float*)d_in[12];
  const float* W_out = (const float*)d_in[13];
  const float* b_out = (const float*)d_in[14];
  float* ws = (float*)d_ws;
  float* out = (float*)d_out;

  setup_kernel<<<8, 256, 0, stream>>>(W_x2h,b_x2h,W_h2h,b_h2h,W_fc2,b_fc2,ln_g,ln_b,
                                      W_fcsa,b_fcsa,W_in,b_in,W_out,b_out, ws);

  void* args[] = { (void*)&ws, (void*)&x, (void*)&out };
  hipLaunchCooperativeKernel((void*)rnn_all, dim3(NBLK), dim3(TPB), args, 0, stream);
}